// Round 13
// baseline (58.197 us; speedup 1.0000x reference)
//
#include <hip/hip_runtime.h>

#define NROWS 32
#define SSTRIP 512    // samples per strip (8 per lane, one wave per strip)
#define NSTRIPS 1875  // strips per row = 960000 / 512
#define SPL 8         // samples per lane
#define FRAME 480
#define LFRAMES 2000

typedef float f32x4 __attribute__((ext_vector_type(4)));  // native clang vec

// Exact f64 value of the f32 reciprocal the ref multiplies by (validated r8).
#define R48000D ((double)(1.0f / 48000.0f))

// XLA-CPU f32 mirror: division-by-constant rewritten to multiply by the f32
// reciprocal (validated round 8). No FMA contraction.
__device__ __forceinline__ void sample_udA(const float* __restrict__ frow,
                                           int L, int t, float& up, float& d) {
  const float R480 = 1.0f / 480.0f;      // RN(1/480)
  const float R48000 = 1.0f / 48000.0f;  // RN(1/48000)
  float x = __fsub_rn(__fmul_rn(__fadd_rn((float)t, 0.5f), R480), 0.5f);
  x = fminf(fmaxf(x, 0.0f), (float)(L - 1));
  const int i0 = (int)x;                    // x >= 0: trunc == floor
  const float w = __fsub_rn(x, (float)i0);  // exact
  const int i1 = min(i0 + 1, L - 1);
  const float a0 = fmaxf(frow[i0], 0.0f);
  const float a1 = fmaxf(frow[i1], 0.0f);
  up = __fadd_rn(__fmul_rn(a0, __fsub_rn(1.0f, w)), __fmul_rn(a1, w));
  d = __fmul_rn(up, R48000);
}

// Per-frame sum of up (in Hz*samples, exact a-values), closed form.
// Algebra validated empirically: r1/r6 and r4/r5 bit-identical absmax pairs.
__device__ __forceinline__ double frame_sum_u(const float* __restrict__ frow,
                                              int l, int L) {
  const double a  = (double)fmaxf(frow[l], 0.0f);
  const double ap = (l > 0) ? (double)fmaxf(frow[l - 1], 0.0f) : 0.0;
  const double an = (l < L - 1) ? (double)fmaxf(frow[l + 1], 0.0f) : 0.0;
  double wp = 60.0, wc = 360.0, wn = 60.0;
  if (l == 0)     { wp = 0.0; wc = 420.0; }
  if (l == L - 1) { wn = 0.0; wc = 420.0; }
  return wp * ap + wc * a + wn * an;
}

// Kernel A: one block per row. Frame sums -> block f64 scan -> framePre in
// LDS -> stripFrac via closed-form partial-frame prefixes.
__global__ __launch_bounds__(1024) void frame_scan(
    const float* __restrict__ f0, float* __restrict__ stripFrac, int L) {
  const int row = blockIdx.x;
  const int tid = threadIdx.x;
  const float* frow = f0 + row * L;

  __shared__ double framePre[LFRAMES];  // exclusive prefix, up-units
  __shared__ double wsum[16];

  // 2 frames per thread (threads 0..999)
  double fs0 = 0.0, fs1 = 0.0;
  const int l0 = tid * 2;
  if (l0 < LFRAMES) {
    fs0 = frame_sum_u(frow, l0, L);
    fs1 = frame_sum_u(frow, l0 + 1, L);
  }
  double local = fs0 + fs1;

  const int lane = tid & 63, wid = tid >> 6;
  double run = local;
#pragma unroll
  for (int sh = 1; sh < 64; sh <<= 1) {
    double o = __shfl_up(run, sh, 64);
    if (lane >= sh) run += o;
  }
  if (lane == 63) wsum[wid] = run;
  __syncthreads();
  if (wid == 0) {
    double wv = (lane < 16) ? wsum[lane] : 0.0;
    double wr = wv;
#pragma unroll
    for (int sh = 1; sh < 16; sh <<= 1) {
      double o = __shfl_up(wr, sh, 64);
      if (lane >= sh) wr += o;
    }
    if (lane < 16) wsum[lane] = wr - wv;  // exclusive wave offsets
  }
  __syncthreads();
  const double base = wsum[wid] + (run - local);  // exclusive thread prefix
  if (l0 < LFRAMES) {
    framePre[l0] = base;
    framePre[l0 + 1] = base + fs0;
  }
  __syncthreads();

  // stripFrac: phase before sample 512*s, closed-form partial within frame.
  for (int s = tid; s < NSTRIPS; s += 1024) {
    const int t0 = s * SSTRIP;
    const int l = t0 / FRAME;
    const int c = t0 - l * FRAME;  // samples of frame l before strip start
    const double a = (double)fmaxf(frow[l], 0.0f);
    double partial;
    if (c == 0) {
      partial = 0.0;
    } else if (c <= 240) {
      if (l == 0) {
        partial = (double)c * a;
      } else {
        const double ap = (double)fmaxf(frow[l - 1], 0.0f);
        partial = (double)c * ap +
                  (a - ap) * ((double)c * (c + 480)) * (1.0 / 960.0);
      }
    } else {
      const double ap = (l > 0) ? (double)fmaxf(frow[l - 1], 0.0f) : a;
      const double H1 = (l == 0) ? 240.0 * a : 60.0 * ap + 180.0 * a;
      const int m0 = c - 240;
      if (l == L - 1) {
        partial = H1 + (double)m0 * a;
      } else {
        const double an = (double)fmaxf(frow[l + 1], 0.0f);
        partial = H1 + (double)m0 * a +
                  (an - a) * ((double)m0 * m0) * (1.0 / 960.0);
      }
    }
    const double p = (framePre[l] + partial) * R48000D;
    stripFrac[(size_t)row * NSTRIPS + s] = (float)(p - floor(p));
  }
}

// Kernel B: one wave per 512-sample strip; 8 contiguous samples per lane ->
// 2x vec4 NT noise loads / NT out stores (streaming data bypasses cache
// allocation; f0/stripFrac keep the caches); one f64 wave scan per strip.
__global__ __launch_bounds__(256) void emit_k(
    const float* __restrict__ f0, const float* __restrict__ noise,
    const float* __restrict__ stripFrac, float* __restrict__ out,
    int L, int T) {
  const int gw = (int)((blockIdx.x * 256u + threadIdx.x) >> 6);
  const int lane = threadIdx.x & 63;
  const int row = gw / NSTRIPS;
  const int strip = gw - row * NSTRIPS;
  if (row >= NROWS) return;
  const float* frow = f0 + row * L;
  const int tb = strip * SSTRIP + lane * SPL;

  float up[SPL];
  float dd[SPL];
  double s = 0.0;
#pragma unroll
  for (int k = 0; k < SPL; ++k) {
    sample_udA(frow, L, tb + k, up[k], dd[k]);
    s += (double)dd[k];
  }

  double run = s;  // inclusive wave scan of per-lane sums
#pragma unroll
  for (int sh = 1; sh < 64; sh <<= 1) {
    double o = __shfl_up(run, sh, 64);
    if (lane >= sh) run += o;
  }
  double ph = (double)stripFrac[(size_t)row * NSTRIPS + strip] + (run - s);

  const f32x4* np_ =
      reinterpret_cast<const f32x4*>(noise + (size_t)row * T + tb);
  const f32x4 nz0 = __builtin_nontemporal_load(np_);
  const f32x4 nz1 = __builtin_nontemporal_load(np_ + 1);
  const float nv[SPL] = {nz0.x, nz0.y, nz0.z, nz0.w,
                         nz1.x, nz1.y, nz1.z, nz1.w};
  float ov[SPL];
#pragma unroll
  for (int k = 0; k < SPL; ++k) {
    ph += (double)dd[k];
    const float fr = (float)(ph - floor(ph));     // revolutions in [0,1)
    const float sn = __builtin_amdgcn_sinf(fr);   // sin(2*pi*fr), v_sin_f32
    const float v = __fadd_rn(sn, __fmul_rn(0.03f, nv[k]));
    const float u = __fmul_rn(0.3f, nv[k]);
    ov[k] = (up[k] > 20.0f) ? v : u;
  }
  f32x4* op_ = reinterpret_cast<f32x4*>(out + (size_t)row * T + tb);
  const f32x4 o0 = {ov[0], ov[1], ov[2], ov[3]};
  const f32x4 o1 = {ov[4], ov[5], ov[6], ov[7]};
  __builtin_nontemporal_store(o0, op_);
  __builtin_nontemporal_store(o1, op_ + 1);
}

extern "C" void kernel_launch(void* const* d_in, const int* in_sizes, int n_in,
                              void* d_out, int out_size, void* d_ws, size_t ws_size,
                              hipStream_t stream) {
  const float* f0    = (const float*)d_in[0];
  const float* noise = (const float*)d_in[1];
  float* out = (float*)d_out;
  float* stripFrac = (float*)d_ws;  // 60000 f32 = 240 KB

  const int L = in_sizes[0] / NROWS;  // 2000
  const int T = in_sizes[1] / NROWS;  // 960000

  frame_scan<<<NROWS, 1024, 0, stream>>>(f0, stripFrac, L);

  const int nWaves = NROWS * NSTRIPS;  // 60000
  const int blocks = nWaves / 4;       // 15000 blocks of 256
  emit_k<<<blocks, 256, 0, stream>>>(f0, noise, stripFrac, out, L, T);
}

// Round 14
// 47.118 us; speedup vs baseline: 1.2351x; 1.2351x over previous
//
#include <hip/hip_runtime.h>

#define NROWS 32
#define SSTRIP 512    // samples per strip (8 per lane, one wave per strip)
#define NSTRIPS 1875  // strips per row = 960000 / 512
#define SPL 8         // samples per lane
#define FRAME 480
#define LFRAMES 2000

// Exact f64 value of the f32 reciprocal the ref multiplies by (validated r8).
#define R48000D ((double)(1.0f / 48000.0f))

// XLA-CPU f32 mirror: division-by-constant rewritten to multiply by the f32
// reciprocal (validated round 8). No FMA contraction.
__device__ __forceinline__ void sample_udA(const float* __restrict__ frow,
                                           int L, int t, float& up, float& d) {
  const float R480 = 1.0f / 480.0f;      // RN(1/480)
  const float R48000 = 1.0f / 48000.0f;  // RN(1/48000)
  float x = __fsub_rn(__fmul_rn(__fadd_rn((float)t, 0.5f), R480), 0.5f);
  x = fminf(fmaxf(x, 0.0f), (float)(L - 1));
  const int i0 = (int)x;                    // x >= 0: trunc == floor
  const float w = __fsub_rn(x, (float)i0);  // exact
  const int i1 = min(i0 + 1, L - 1);
  const float a0 = fmaxf(frow[i0], 0.0f);
  const float a1 = fmaxf(frow[i1], 0.0f);
  up = __fadd_rn(__fmul_rn(a0, __fsub_rn(1.0f, w)), __fmul_rn(a1, w));
  d = __fmul_rn(up, R48000);
}

// Per-frame sum of up (in Hz*samples, exact a-values), closed form.
// Algebra validated empirically: r1/r6 and r4/r5 bit-identical absmax pairs.
__device__ __forceinline__ double frame_sum_u(const float* __restrict__ frow,
                                              int l, int L) {
  const double a  = (double)fmaxf(frow[l], 0.0f);
  const double ap = (l > 0) ? (double)fmaxf(frow[l - 1], 0.0f) : 0.0;
  const double an = (l < L - 1) ? (double)fmaxf(frow[l + 1], 0.0f) : 0.0;
  double wp = 60.0, wc = 360.0, wn = 60.0;
  if (l == 0)     { wp = 0.0; wc = 420.0; }
  if (l == L - 1) { wn = 0.0; wc = 420.0; }
  return wp * ap + wc * a + wn * an;
}

// Kernel A: one block per row. Frame sums -> block f64 scan -> framePre in
// LDS -> stripFrac via closed-form partial-frame prefixes.
__global__ __launch_bounds__(1024) void frame_scan(
    const float* __restrict__ f0, float* __restrict__ stripFrac, int L) {
  const int row = blockIdx.x;
  const int tid = threadIdx.x;
  const float* frow = f0 + row * L;

  __shared__ double framePre[LFRAMES];  // exclusive prefix, up-units
  __shared__ double wsum[16];

  // 2 frames per thread (threads 0..999)
  double fs0 = 0.0, fs1 = 0.0;
  const int l0 = tid * 2;
  if (l0 < LFRAMES) {
    fs0 = frame_sum_u(frow, l0, L);
    fs1 = frame_sum_u(frow, l0 + 1, L);
  }
  double local = fs0 + fs1;

  const int lane = tid & 63, wid = tid >> 6;
  double run = local;
#pragma unroll
  for (int sh = 1; sh < 64; sh <<= 1) {
    double o = __shfl_up(run, sh, 64);
    if (lane >= sh) run += o;
  }
  if (lane == 63) wsum[wid] = run;
  __syncthreads();
  if (wid == 0) {
    double wv = (lane < 16) ? wsum[lane] : 0.0;
    double wr = wv;
#pragma unroll
    for (int sh = 1; sh < 16; sh <<= 1) {
      double o = __shfl_up(wr, sh, 64);
      if (lane >= sh) wr += o;
    }
    if (lane < 16) wsum[lane] = wr - wv;  // exclusive wave offsets
  }
  __syncthreads();
  const double base = wsum[wid] + (run - local);  // exclusive thread prefix
  if (l0 < LFRAMES) {
    framePre[l0] = base;
    framePre[l0 + 1] = base + fs0;
  }
  __syncthreads();

  // stripFrac: phase before sample 512*s, closed-form partial within frame.
  for (int s = tid; s < NSTRIPS; s += 1024) {
    const int t0 = s * SSTRIP;
    const int l = t0 / FRAME;
    const int c = t0 - l * FRAME;  // samples of frame l before strip start
    const double a = (double)fmaxf(frow[l], 0.0f);
    double partial;
    if (c == 0) {
      partial = 0.0;
    } else if (c <= 240) {
      if (l == 0) {
        partial = (double)c * a;
      } else {
        const double ap = (double)fmaxf(frow[l - 1], 0.0f);
        partial = (double)c * ap +
                  (a - ap) * ((double)c * (c + 480)) * (1.0 / 960.0);
      }
    } else {
      const double ap = (l > 0) ? (double)fmaxf(frow[l - 1], 0.0f) : a;
      const double H1 = (l == 0) ? 240.0 * a : 60.0 * ap + 180.0 * a;
      const int m0 = c - 240;
      if (l == L - 1) {
        partial = H1 + (double)m0 * a;
      } else {
        const double an = (double)fmaxf(frow[l + 1], 0.0f);
        partial = H1 + (double)m0 * a +
                  (an - a) * ((double)m0 * m0) * (1.0 / 960.0);
      }
    }
    const double p = (framePre[l] + partial) * R48000D;
    stripFrac[(size_t)row * NSTRIPS + s] = (float)(p - floor(p));
  }
}

// Kernel B: one wave per 512-sample strip; 8 contiguous samples per lane ->
// 2x float4 noise/out; one f64 wave scan per strip, per-lane running phase.
__global__ __launch_bounds__(256) void emit_k(
    const float* __restrict__ f0, const float* __restrict__ noise,
    const float* __restrict__ stripFrac, float* __restrict__ out,
    int L, int T) {
  const int gw = (int)((blockIdx.x * 256u + threadIdx.x) >> 6);
  const int lane = threadIdx.x & 63;
  const int row = gw / NSTRIPS;
  const int strip = gw - row * NSTRIPS;
  if (row >= NROWS) return;
  const float* frow = f0 + row * L;
  const int tb = strip * SSTRIP + lane * SPL;

  float up[SPL];
  float dd[SPL];
  double s = 0.0;
#pragma unroll
  for (int k = 0; k < SPL; ++k) {
    sample_udA(frow, L, tb + k, up[k], dd[k]);
    s += (double)dd[k];
  }

  double run = s;  // inclusive wave scan of per-lane sums
#pragma unroll
  for (int sh = 1; sh < 64; sh <<= 1) {
    double o = __shfl_up(run, sh, 64);
    if (lane >= sh) run += o;
  }
  double ph = (double)stripFrac[(size_t)row * NSTRIPS + strip] + (run - s);

  const float* np_ = noise + (size_t)row * T + tb;
  const float4 nz0 = *reinterpret_cast<const float4*>(np_);
  const float4 nz1 = *reinterpret_cast<const float4*>(np_ + 4);
  const float nv[SPL] = {nz0.x, nz0.y, nz0.z, nz0.w,
                         nz1.x, nz1.y, nz1.z, nz1.w};
  float ov[SPL];
#pragma unroll
  for (int k = 0; k < SPL; ++k) {
    ph += (double)dd[k];
    const float fr = (float)(ph - floor(ph));     // revolutions in [0,1)
    const float sn = __builtin_amdgcn_sinf(fr);   // sin(2*pi*fr), v_sin_f32
    const float v = __fadd_rn(sn, __fmul_rn(0.03f, nv[k]));
    const float u = __fmul_rn(0.3f, nv[k]);
    ov[k] = (up[k] > 20.0f) ? v : u;
  }
  float* op_ = out + (size_t)row * T + tb;
  *reinterpret_cast<float4*>(op_) = make_float4(ov[0], ov[1], ov[2], ov[3]);
  *reinterpret_cast<float4*>(op_ + 4) = make_float4(ov[4], ov[5], ov[6], ov[7]);
}

extern "C" void kernel_launch(void* const* d_in, const int* in_sizes, int n_in,
                              void* d_out, int out_size, void* d_ws, size_t ws_size,
                              hipStream_t stream) {
  const float* f0    = (const float*)d_in[0];
  const float* noise = (const float*)d_in[1];
  float* out = (float*)d_out;
  float* stripFrac = (float*)d_ws;  // 60000 f32 = 240 KB

  const int L = in_sizes[0] / NROWS;  // 2000
  const int T = in_sizes[1] / NROWS;  // 960000

  frame_scan<<<NROWS, 1024, 0, stream>>>(f0, stripFrac, L);

  const int nWaves = NROWS * NSTRIPS;  // 60000
  const int blocks = nWaves / 4;       // 15000 blocks of 256
  emit_k<<<blocks, 256, 0, stream>>>(f0, noise, stripFrac, out, L, T);
}